// Round 6
// baseline (644.001 us; speedup 1.0000x reference)
//
#include <hip/hip_runtime.h>
#include <hip/hip_bf16.h>
#include <stdint.h>

// Problem constants
#define B_ 4
#define S_ 2048
#define D_ 256
#define H_ 8

using f32x4  = __attribute__((ext_vector_type(4))) float;
using f32x16 = __attribute__((ext_vector_type(16))) float;
using bf16x4 = __attribute__((ext_vector_type(4))) __bf16;
using bf16x8 = __attribute__((ext_vector_type(8))) __bf16;

static __device__ __forceinline__ unsigned short f2bf(float x) {
    union { float f; unsigned u; } v; v.f = x;
    unsigned r = (v.u + 0x7FFFu + ((v.u >> 16) & 1u)) >> 16;
    return (unsigned short)r;
}

static __device__ __forceinline__ f32x4 mfma16(bf16x8 a, bf16x8 b, f32x4 c) {
    return __builtin_amdgcn_mfma_f32_16x16x32_bf16(a, b, c, 0, 0, 0);
}
static __device__ __forceinline__ f32x16 mfma32(bf16x8 a, bf16x8 b, f32x16 c) {
    return __builtin_amdgcn_mfma_f32_32x32x16_bf16(a, b, c, 0, 0, 0);
}

static __device__ __forceinline__ unsigned cvt_pk_bf16(float lo, float hi) {
    unsigned r;
    asm volatile("v_cvt_pk_bf16_f32 %0, %1, %2" : "=v"(r) : "v"(lo), "v"(hi));
    return r;
}

static __device__ __forceinline__ void gl_lds16(const void* g, void* l) {
    __builtin_amdgcn_global_load_lds((const __attribute__((address_space(1))) void*)g,
                                     (__attribute__((address_space(3))) void*)l, 16, 0, 0);
}
static __device__ __forceinline__ void gl_lds4(const void* g, void* l) {
    __builtin_amdgcn_global_load_lds((const __attribute__((address_space(1))) void*)g,
                                     (__attribute__((address_space(3))) void*)l, 4, 0, 0);
}

// Explicit drain of all outstanding VMEM (incl. global_load_lds DMA) before a
// barrier. Do NOT rely on the compiler's implicit vmcnt at __syncthreads —
// LDS-DMA tracking across control flow is the prime race suspect (m152/T4).
static __device__ __forceinline__ void drain_vmem_then_sync() {
    asm volatile("s_waitcnt vmcnt(0)" ::: "memory");
    __builtin_amdgcn_sched_barrier(0);
    __syncthreads();
}

// ---------------------------------------------------------------------------
// Kernel 0: transpose + bf16-convert weights. (unchanged)
// ---------------------------------------------------------------------------
__global__ __launch_bounds__(256) void wtrans_kernel(
        const float* __restrict__ Wq, const float* __restrict__ Wk,
        const float* __restrict__ Wv, const float* __restrict__ Wmh,
        unsigned short* __restrict__ WqkvT, unsigned short* __restrict__ WmhT) {
    int idx = blockIdx.x * 256 + threadIdx.x;
    const int NQKV = 3 * H_ * 256 * 256;
    if (idx < NQKV) {
        int d = idx & 255, n = (idx >> 8) & 255, h = (idx >> 16) & 7, which = idx >> 19;
        const float* W = (which == 0) ? Wq : ((which == 1) ? Wk : Wv);
        WqkvT[idx] = f2bf(W[(h * 256 + d) * 256 + n]);
    } else {
        int j = idx - NQKV;
        int k = j & 2047, n = j >> 11;
        WmhT[j] = f2bf(Wmh[k * 256 + n]);
    }
}

// ---------------------------------------------------------------------------
// Kernel 1: projections (1/16 scale folded into Qh).
// ---------------------------------------------------------------------------
__global__ __launch_bounds__(256, 2) void proj_kernel(
        const float* __restrict__ Q, const float* __restrict__ K,
        const float* __restrict__ V, const unsigned short* __restrict__ WqkvT,
        unsigned short* __restrict__ Qh, unsigned short* __restrict__ Kh,
        unsigned short* __restrict__ VhT) {
    __shared__ __attribute__((aligned(16))) unsigned char smem[65536];
    int tid = threadIdx.x;
    int nt = blockIdx.x & 3, h = (blockIdx.x >> 2) & 7, which = blockIdx.x >> 5;
    int mt = blockIdx.y;
    const float* X = (which == 0) ? Q : ((which == 1) ? K : V);

    {
        const float4* Xv = (const float4*)(X + (size_t)mt * 64 * 256);
        #pragma unroll
        for (int j = 0; j < 16; ++j) {
            int c = tid + 256 * j;
            int row = c >> 6, c4 = c & 63;
            float4 x = Xv[c];
            ushort4 p;
            p.x = f2bf(x.x); p.y = f2bf(x.y); p.z = f2bf(x.z); p.w = f2bf(x.w);
            *(ushort4*)(smem + row * 512 + ((c4 * 8) ^ ((row & 7) << 4))) = p;
        }
    }
    {
        const uint4* Wv_ = (const uint4*)(WqkvT + (size_t)((which * H_ + h) * 256 + nt * 64) * 256);
        #pragma unroll
        for (int j = 0; j < 8; ++j) {
            int c = tid + 256 * j;
            int row = c >> 5, slot = c & 31;
            *(uint4*)(smem + 32768 + row * 512 + ((slot * 16) ^ ((row & 7) << 4))) = Wv_[c];
        }
    }
    __syncthreads();

    int w = tid >> 6, l = tid & 63, lr = l & 15, lg = l >> 4;
    f32x4 acc[4];
    #pragma unroll
    for (int fr = 0; fr < 4; ++fr) acc[fr] = (f32x4){0.f, 0.f, 0.f, 0.f};

    #pragma unroll
    for (int ks = 0; ks < 8; ++ks) {
        int arow = 16 * w + lr;
        bf16x8 a = *(const bf16x8*)(smem + arow * 512 + ((64 * ks + 16 * lg) ^ ((arow & 7) << 4)));
        #pragma unroll
        for (int fr = 0; fr < 4; ++fr) {
            int brow = 16 * fr + lr;
            bf16x8 b = *(const bf16x8*)(smem + 32768 + brow * 512 + ((64 * ks + 16 * lg) ^ ((brow & 7) << 4)));
            acc[fr] = mfma16(a, b, acc[fr]);
        }
    }

    int m0 = mt * 64 + 16 * w + 4 * lg;
    int b = m0 >> 11, s0 = m0 & 2047;
    if (which < 2) {
        unsigned short* out = (which == 0) ? Qh : Kh;
        float sc = (which == 0) ? 0.0625f : 1.0f;   // fold 1/sqrt(dk) into Qh
        #pragma unroll
        for (int fr = 0; fr < 4; ++fr) {
            int n = nt * 64 + 16 * fr + lr;
            #pragma unroll
            for (int i = 0; i < 4; ++i)
                out[(size_t)((b * H_ + h) * S_ + s0 + i) * D_ + n] = f2bf(acc[fr][i] * sc);
        }
    } else {
        #pragma unroll
        for (int fr = 0; fr < 4; ++fr) {
            int n = nt * 64 + 16 * fr + lr;
            ushort4 p;
            p.x = f2bf(acc[fr][0]); p.y = f2bf(acc[fr][1]);
            p.z = f2bf(acc[fr][2]); p.w = f2bf(acc[fr][3]);
            *(ushort4*)(VhT + (size_t)((b * H_ + h) * D_ + n) * S_ + s0) = p;
        }
    }
}

// ---------------------------------------------------------------------------
// Kernel 2: flash attention, swapped-operand 32x32 design.
// Block = 512 threads = 8 waves = 4 q-groups x 2 t-slices; q=128 rows/block.
// S^T = mfma32(Kfrag, Qfrag): lane owns one q column -> lane-local softmax.
// O^T = mfma32(VTfrag, P^Tfrag): stats stay lane-local.
// Staging: global_load_lds, double-buffered, UNCONDITIONAL stage each iter,
// explicit vmcnt(0) drain before every barrier.
// ---------------------------------------------------------------------------
__global__ __launch_bounds__(512, 2) void attn2_kernel(
        const unsigned short* Qh, const unsigned short* __restrict__ Kh,
        const unsigned short* __restrict__ VhT, const float* __restrict__ M,
        unsigned short* heads) {
    __shared__ __attribute__((aligned(16))) unsigned char smem[131072];
    // [0,32K) [32K,64K): K bufs ; [64K,96K) [96K,128K): VT bufs
    const int tid = threadIdx.x;
    const int w = tid >> 6, l = tid & 63;
    const int qg = w >> 1, ts = w & 1;
    const int ql = l & 31, hi = l >> 5;

    // grid decode: all 8 heads of one (b,qt) M-tile land on one XCD.
    int n = blockIdx.x;
    int x = n & 7, r0 = n >> 3;
    int h = r0 & 7, ghi = r0 >> 3;
    int g = x + 8 * ghi;
    int qt = g & 15, b = g >> 4;
    int bh = b * H_ + h;

    const unsigned short* KhP = Kh + (size_t)bh * S_ * D_;
    const unsigned short* VTP = VhT + (size_t)bh * D_ * S_;

    const int q = qt * 128 + qg * 32 + ql;
    const float* MrowP = M + (size_t)b * S_ * S_ + (size_t)q * S_;

    // Q fragments (B-operand): lane holds Qh[q][16*ks+8*hi .. +7]
    bf16x8 qf[16];
    {
        const unsigned short* QhP = Qh + ((size_t)bh * S_ + q) * D_;
        #pragma unroll
        for (int ks = 0; ks < 16; ++ks)
            qf[ks] = *(const bf16x8*)(QhP + ks * 16 + hi * 8);
    }

    f32x16 o[8];
    #pragma unroll
    for (int vb = 0; vb < 8; ++vb) o[vb] = (f32x16){};
    float mrun = -1e30f, lrun = 0.f;

    // per-lane LDS read bases (buffer-relative)
    const int krow = ts * 32 + ql;
    const unsigned kbase = (unsigned)(krow * 512 + ((hi * 16) ^ ((krow & 15) << 5)));
    const unsigned vtbase = (unsigned)(ql * 128 + (((ts * 64) | (hi * 16)) ^ ((ql & 15) << 3)));

    // staging geometry
    const int ksr = 8 * w + (l >> 5);          // + 2j : K tile row
    const unsigned kcol = (l & 31) * 16;
    const int vsr = 32 * w + (l >> 5);         // + 2i : VT tile row
    const unsigned vcol = (l & 31) * 4;

    int cur = 0;

    auto stage = [&](int tt, int bsel) {
        unsigned char* kb = smem + bsel * 32768;
        unsigned char* vb = smem + 65536 + bsel * 32768;
        #pragma unroll
        for (int j = 0; j < 4; ++j) {
            int row = ksr + 2 * j;
            const unsigned char* src = (const unsigned char*)KhP +
                (size_t)(tt * 64 + row) * 512 + (kcol ^ ((row & 15) << 5));
            gl_lds16(src, kb + (8 * w + 2 * j) * 512);
        }
        #pragma unroll
        for (int i = 0; i < 16; ++i) {
            int v = vsr + 2 * i;
            const unsigned char* src = (const unsigned char*)VTP +
                (size_t)v * (S_ * 2) + tt * 128 + (vcol ^ ((v & 15) << 3));
            gl_lds4(src, vb + (32 * w + 2 * i) * 128);
        }
    };

    stage(0, 0);
    drain_vmem_then_sync();

    #pragma unroll 1
    for (int tt = 0; tt < 32; ++tt) {
        stage((tt + 1) & 31, cur ^ 1);   // unconditional: straight-line staging

        const unsigned char* kp = smem + cur * 32768;
        const unsigned char* vp = smem + 65536 + cur * 32768;

        // M mask loads (hidden under QK^T)
        const float* Mt = MrowP + tt * 64 + ts * 32 + 4 * hi;
        float4 mv0 = *(const float4*)(Mt);
        float4 mv1 = *(const float4*)(Mt + 8);
        float4 mv2 = *(const float4*)(Mt + 16);
        float4 mv3 = *(const float4*)(Mt + 24);

        // QK^T : S^T[t][q]
        f32x16 sacc = (f32x16){};
        #pragma unroll
        for (int ks = 0; ks < 16; ++ks) {
            bf16x8 a = *(const bf16x8*)(kp + (kbase ^ (unsigned)(ks * 32)));
            sacc = mfma32(a, qf[ks], sacc);
        }

        // scale*mask (scale pre-folded into Qh), then online softmax (lane-local)
        float p[16];
        #pragma unroll
        for (int rg = 0; rg < 4; ++rg) {
            float4 mv = (rg == 0) ? mv0 : (rg == 1) ? mv1 : (rg == 2) ? mv2 : mv3;
            #pragma unroll
            for (int j = 0; j < 4; ++j) p[4 * rg + j] = sacc[4 * rg + j] * ((const float*)&mv)[j];
        }

        float tm = p[0];
        #pragma unroll
        for (int i = 1; i < 16; ++i) tm = fmaxf(tm, p[i]);
        float tmm = fmaxf(tm, __shfl_xor(tm, 32, 64));

        if (__any(tmm > mrun)) {
            float nm = fmaxf(mrun, tmm);
            float f = __expf(mrun - nm);
            #pragma unroll
            for (int vb = 0; vb < 8; ++vb) o[vb] *= f;
            lrun *= f;
            mrun = nm;
        }

        float rs = 0.f;
        #pragma unroll
        for (int i = 0; i < 16; ++i) { p[i] = __expf(p[i] - mrun); rs += p[i]; }
        lrun += rs;

        // pack P -> bf16, exchange halves with lane^32, build B-frags
        unsigned own0 = cvt_pk_bf16(p[0], p[1]),  own1 = cvt_pk_bf16(p[2], p[3]);
        unsigned own2 = cvt_pk_bf16(p[4], p[5]),  own3 = cvt_pk_bf16(p[6], p[7]);
        unsigned own4 = cvt_pk_bf16(p[8], p[9]),  own5 = cvt_pk_bf16(p[10], p[11]);
        unsigned own6 = cvt_pk_bf16(p[12], p[13]), own7 = cvt_pk_bf16(p[14], p[15]);
        unsigned rec0 = __shfl_xor((int)own0, 32, 64), rec1 = __shfl_xor((int)own1, 32, 64);
        unsigned rec2 = __shfl_xor((int)own2, 32, 64), rec3 = __shfl_xor((int)own3, 32, 64);
        unsigned rec4 = __shfl_xor((int)own4, 32, 64), rec5 = __shfl_xor((int)own5, 32, 64);
        unsigned rec6 = __shfl_xor((int)own6, 32, 64), rec7 = __shfl_xor((int)own7, 32, 64);

        union { unsigned u[4]; bf16x8 v; } f0, f1;
        f0.u[0] = hi ? rec2 : own0;  f0.u[1] = hi ? rec3 : own1;
        f0.u[2] = hi ? own2 : rec0;  f0.u[3] = hi ? own3 : rec1;
        f1.u[0] = hi ? rec6 : own4;  f1.u[1] = hi ? rec7 : own5;
        f1.u[2] = hi ? own6 : rec4;  f1.u[3] = hi ? own7 : rec5;

        // PV : O^T[v][q] += V^T[v][t] * P^T[t][q]
        #pragma unroll
        for (int tstep = 0; tstep < 2; ++tstep) {
            bf16x8 pf = tstep ? f1.v : f0.v;
            unsigned a0 = vtbase ^ (unsigned)(tstep * 32);
            #pragma unroll
            for (int vb = 0; vb < 8; ++vb) {
                bf16x4 lo4 = *(const bf16x4*)(vp + vb * 4096 + a0);
                bf16x4 hi4 = *(const bf16x4*)(vp + vb * 4096 + (a0 ^ 8u));
                bf16x8 av = __builtin_shufflevector(lo4, hi4, 0, 1, 2, 3, 4, 5, 6, 7);
                o[vb] = mfma32(av, pf, o[vb]);
            }
        }

        drain_vmem_then_sync();
        cur ^= 1;
    }

    // ---- epilogue: hi-merge of l, ts-merge of (m,l,O) via LDS ----
    lrun += __shfl_xor(lrun, 32, 64);

    float2* mlb = (float2*)smem;
    if (hi == 0) mlb[(qg * 2 + ts) * 32 + ql] = make_float2(mrun, lrun);
    __syncthreads();
    float2 oth = mlb[(qg * 2 + (ts ^ 1)) * 32 + ql];
    __syncthreads();

    float mstar = fmaxf(mrun, oth.x);
    float aS = __expf(mrun - mstar), aO = __expf(oth.x - mstar);
    float inv = 1.f / (aS * lrun + aO * oth.y);
    float sc = aS * inv;
    #pragma unroll
    for (int vb = 0; vb < 8; ++vb) o[vb] *= sc;

    float* ob = (float*)smem;   // [qg][v(256)][q(32)] f32 = 128KB
    if (ts == 1) {
        #pragma unroll
        for (int vb = 0; vb < 8; ++vb)
            #pragma unroll
            for (int r = 0; r < 16; ++r) {
                int v = 32 * vb + (r & 3) + 8 * (r >> 2) + 4 * hi;
                ob[qg * 8192 + v * 32 + ql] = o[vb][r];
            }
    }
    __syncthreads();
    if (ts == 0) {
        unsigned short* hp = heads + ((size_t)bh * S_ + q) * D_;
        #pragma unroll
        for (int vb = 0; vb < 8; ++vb) {
            #pragma unroll
            for (int rg = 0; rg < 4; ++rg) {
                int v0 = 32 * vb + 8 * rg + 4 * hi;
                ushort4 pk;
                pk.x = f2bf(o[vb][4 * rg + 0] + ob[qg * 8192 + (v0 + 0) * 32 + ql]);
                pk.y = f2bf(o[vb][4 * rg + 1] + ob[qg * 8192 + (v0 + 1) * 32 + ql]);
                pk.z = f2bf(o[vb][4 * rg + 2] + ob[qg * 8192 + (v0 + 2) * 32 + ql]);
                pk.w = f2bf(o[vb][4 * rg + 3] + ob[qg * 8192 + (v0 + 3) * 32 + ql]);
                *(ushort4*)(hp + v0) = pk;
            }
        }
    }
}

// ---------------------------------------------------------------------------
// Kernel 3: output projection (unchanged).
// ---------------------------------------------------------------------------
__global__ __launch_bounds__(256, 2) void out_kernel(
        const unsigned short* __restrict__ heads,
        const unsigned short* __restrict__ WmhT, float* __restrict__ out) {
    __shared__ __attribute__((aligned(16))) unsigned char smem[65536];
    int tid = threadIdx.x;
    int nt = blockIdx.x, mt = blockIdx.y;
    int w = tid >> 6, l = tid & 63, lr = l & 15, lg = l >> 4;
    int m0 = mt * 64;
    int b = m0 >> 11, s00 = m0 & 2047;

    f32x4 acc[4];
    #pragma unroll
    for (int fr = 0; fr < 4; ++fr) acc[fr] = (f32x4){0.f, 0.f, 0.f, 0.f};

    for (int h = 0; h < H_; ++h) {
        __syncthreads();
        {
            const uint4* src = (const uint4*)(heads + (size_t)((b * H_ + h) * S_ + s00) * D_);
            #pragma unroll
            for (int j = 0; j < 8; ++j) {
                int c = tid + 256 * j;
                int row = c >> 5, slot = c & 31;
                *(uint4*)(smem + row * 512 + ((slot * 16) ^ ((row & 7) << 4))) = src[c];
            }
        }
        {
            #pragma unroll
            for (int j = 0; j < 8; ++j) {
                int c = tid + 256 * j;
                int row = c >> 5, slot = c & 31;
                uint4 xx = *(const uint4*)(WmhT + (size_t)(nt * 64 + row) * 2048 + h * 256 + slot * 8);
                *(uint4*)(smem + 32768 + row * 512 + ((slot * 16) ^ ((row & 7) << 4))) = xx;
            }
        }
        __syncthreads();
        #pragma unroll
        for (int ks = 0; ks < 8; ++ks) {
            int arow = 16 * w + lr;
            bf16x8 a = *(const bf16x8*)(smem + arow * 512 + ((64 * ks + 16 * lg) ^ ((arow & 7) << 4)));
            #pragma unroll
            for (int fr = 0; fr < 4; ++fr) {
                int brow = 16 * fr + lr;
                bf16x8 bb = *(const bf16x8*)(smem + 32768 + brow * 512 + ((64 * ks + 16 * lg) ^ ((brow & 7) << 4)));
                acc[fr] = mfma16(a, bb, acc[fr]);
            }
        }
    }

    int mrow = mt * 64 + 16 * w + 4 * lg;
    #pragma unroll
    for (int fr = 0; fr < 4; ++fr) {
        int nn = nt * 64 + 16 * fr + lr;
        #pragma unroll
        for (int i = 0; i < 4; ++i)
            out[(size_t)(mrow + i) * D_ + nn] = acc[fr][i];
    }
}

// ---------------------------------------------------------------------------
extern "C" void kernel_launch(void* const* d_in, const int* in_sizes, int n_in,
                              void* d_out, int out_size, void* d_ws, size_t ws_size,
                              hipStream_t stream) {
    const float* Q   = (const float*)d_in[0];
    const float* K   = (const float*)d_in[1];
    const float* V   = (const float*)d_in[2];
    const float* M   = (const float*)d_in[3];
    const float* Wq  = (const float*)d_in[4];
    const float* Wk  = (const float*)d_in[5];
    const float* Wv  = (const float*)d_in[6];
    const float* Wmh = (const float*)d_in[7];
    float* out = (float*)d_out;

    char* ws = (char*)d_ws;
    unsigned short* Qh    = (unsigned short*)(ws);
    unsigned short* Kh    = (unsigned short*)(ws + 33554432);
    unsigned short* VhT   = (unsigned short*)(ws + 67108864);
    unsigned short* WqkvT = (unsigned short*)(ws + 100663296);
    unsigned short* WmhT  = (unsigned short*)(ws + 103809024);

    wtrans_kernel<<<dim3(8192), dim3(256), 0, stream>>>(Wq, Wk, Wv, Wmh, WqkvT, WmhT);
    proj_kernel<<<dim3(96, 128), dim3(256), 0, stream>>>(Q, K, V, WqkvT, Qh, Kh, VhT);
    attn2_kernel<<<dim3(512), dim3(512), 0, stream>>>(Qh, Kh, VhT, M, /*heads=*/Qh);
    out_kernel<<<dim3(4, 128), dim3(256), 0, stream>>>(/*heads=*/Qh, WmhT, out);
}